// Round 1
// baseline (298.372 us; speedup 1.0000x reference)
//
#include <hip/hip_runtime.h>
#include <hip/hip_bf16.h>
#include <math.h>

// Problem constants
#define BQ 4
#define NQ 100
#define MQ 50
#define HWSZ 65536
#define NP 112   // padded N (7 x 16)
#define MP 64    // padded M (4 x 16)
#define BK 64    // K depth per LDS stage
#define LDA 72   // LDS row stride in bf16 elems (64 + 8 pad -> 144B, 16B-aligned, even bank spread)
#define EPSV 1e-6f

typedef __attribute__((ext_vector_type(8))) short short8;
typedef __attribute__((ext_vector_type(4))) float f32x4;

__device__ inline unsigned short f2bf(float f) {
    unsigned u = __float_as_uint(f);
    unsigned r = u + 0x7FFFu + ((u >> 16) & 1u);   // RTNE
    return (unsigned short)(r >> 16);
}

__device__ inline void xform(float x, float& d, float& pm, float& l1m) {
    float e = __expf(-x);
    float s = 1.0f / (1.0f + e);                    // sigmoid (x->-inf: e=inf -> s=0; x->+inf: s=1)
    pm = fminf(fmaxf(s, EPSV), 1.0f - EPSV);        // clip like reference
    float lp = __logf(pm);
    l1m = __logf(1.0f - pm);
    d = lp - l1m;
}

// Main fused kernel: grid (nch, 4). Each block handles K range [chunk*Kc, (chunk+1)*Kc)
// for batch b, producing partial S1[n][m] = sum d*tm, S2[n][m] = sum pm*tm over its K range,
// plus row-sum partials (l1m, pm per n) and tm column sums (per m).
__global__ __launch_bounds__(256, 2)
void matcher_main(const float* __restrict__ pred_masks,  // [4][100][65536]
                  const float* __restrict__ tgt_masks,   // [4][50][65536]
                  float* __restrict__ part1,             // [4][nch][112][64]
                  float* __restrict__ part2,             // [4][nch][112][64]
                  float* __restrict__ rspart,            // [4][nch][112][2]  (l1m, pm)
                  float* __restrict__ tspart,            // [4][nch][64]
                  int nch, int Kc)
{
    __shared__ __align__(16) unsigned short ldsAd[NP * LDA];
    __shared__ __align__(16) unsigned short ldsApm[NP * LDA];
    __shared__ __align__(16) unsigned short ldsB[MP * LDA];

    const int chunk = blockIdx.x;
    const int b     = blockIdx.y;
    const int t     = threadIdx.x;
    const int lane  = t & 63;
    const int wv    = t >> 6;    // wave id = m-tile
    const int kq    = t & 15;    // k-quad (4 floats) within BK
    const int rg    = t >> 4;    // row group 0..15

    const long kbase0 = (long)chunk * Kc;
    const int nsteps = Kc / BK;

    f32x4 acc1[7], acc2[7];
    for (int i = 0; i < 7; i++) { acc1[i] = (f32x4){0.f,0.f,0.f,0.f}; acc2[i] = (f32x4){0.f,0.f,0.f,0.f}; }
    float rsl[7], rsp[7];
    for (int i = 0; i < 7; i++) { rsl[i] = 0.f; rsp[i] = 0.f; }
    float ts4[4];
    for (int i = 0; i < 4; i++) ts4[i] = 0.f;

    const int aoff = (lane & 15) * LDA;       // row-in-tile LDS offset
    const int koff = (lane >> 4) * 8;         // k offset within k-step

    for (int s = 0; s < nsteps; ++s) {
        const long kb = kbase0 + (long)s * BK;

        // ---- stage A (pred_masks -> d, pm in bf16), rows 0..111 (>=100 zero) ----
        #pragma unroll
        for (int i = 0; i < 7; i++) {
            int row = i * 16 + rg;
            unsigned d0=0,d1=0,p0=0,p1=0;   // packed bf16 pairs (zeros for pad rows)
            if (row < NQ) {
                const float4 v = *(const float4*)&pred_masks[((long)(b * NQ + row)) * HWSZ + kb + kq * 4];
                float dd, pp, ll;
                xform(v.x, dd, pp, ll); rsl[i] += ll; rsp[i] += pp;
                unsigned short dh0 = f2bf(dd), ph0 = f2bf(pp);
                xform(v.y, dd, pp, ll); rsl[i] += ll; rsp[i] += pp;
                d0 = (unsigned)dh0 | ((unsigned)f2bf(dd) << 16);
                p0 = (unsigned)ph0 | ((unsigned)f2bf(pp) << 16);
                xform(v.z, dd, pp, ll); rsl[i] += ll; rsp[i] += pp;
                unsigned short dh2 = f2bf(dd), ph2 = f2bf(pp);
                xform(v.w, dd, pp, ll); rsl[i] += ll; rsp[i] += pp;
                d1 = (unsigned)dh2 | ((unsigned)f2bf(dd) << 16);
                p1 = (unsigned)ph2 | ((unsigned)f2bf(pp) << 16);
            }
            *(uint2*)&ldsAd[row * LDA + kq * 4]  = make_uint2(d0, d1);
            *(uint2*)&ldsApm[row * LDA + kq * 4] = make_uint2(p0, p1);
        }

        // ---- stage B (tgt_masks bf16), rows 0..63 (>=50 zero) ----
        #pragma unroll
        for (int i = 0; i < 4; i++) {
            int row = i * 16 + rg;
            unsigned b0 = 0, b1 = 0;
            if (row < MQ) {
                const float4 v = *(const float4*)&tgt_masks[((long)(b * MQ + row)) * HWSZ + kb + kq * 4];
                ts4[i] += v.x + v.y + v.z + v.w;
                b0 = (unsigned)f2bf(v.x) | ((unsigned)f2bf(v.y) << 16);
                b1 = (unsigned)f2bf(v.z) | ((unsigned)f2bf(v.w) << 16);
            }
            *(uint2*)&ldsB[row * LDA + kq * 4] = make_uint2(b0, b1);
        }

        __syncthreads();

        // ---- MFMA: wave wv handles m-tile wv, all 7 n-tiles, both matrices ----
        #pragma unroll
        for (int ks = 0; ks < 2; ++ks) {
            const int kk = ks * 32 + koff;
            const short8 bf = *(const short8*)&ldsB[(wv * 16) * LDA + aoff + kk];
            #pragma unroll
            for (int nt = 0; nt < 7; ++nt) {
                const short8 a1 = *(const short8*)&ldsAd[(nt * 16) * LDA + aoff + kk];
                acc1[nt] = __builtin_amdgcn_mfma_f32_16x16x32_bf16(a1, bf, acc1[nt], 0, 0, 0);
                const short8 a2 = *(const short8*)&ldsApm[(nt * 16) * LDA + aoff + kk];
                acc2[nt] = __builtin_amdgcn_mfma_f32_16x16x32_bf16(a2, bf, acc2[nt], 0, 0, 0);
            }
        }

        __syncthreads();
    }

    // ---- store C partials: C/D layout col=lane&15, row=(lane>>4)*4+reg ----
    const long pbase = ((long)(b * nch + chunk)) * NP * MP;
    const int mloc = wv * 16 + (lane & 15);
    const int nr0 = (lane >> 4) * 4;
    #pragma unroll
    for (int nt = 0; nt < 7; ++nt) {
        #pragma unroll
        for (int r = 0; r < 4; ++r) {
            const int n = nt * 16 + nr0 + r;
            part1[pbase + n * MP + mloc] = acc1[nt][r];
            part2[pbase + n * MP + mloc] = acc2[nt][r];
        }
    }

    // ---- row-sum / col-sum reductions via LDS (reuse A/Apm buffers) ----
    float2* red = (float2*)ldsAd;   // [112][16]
    #pragma unroll
    for (int i = 0; i < 7; i++) red[(i * 16 + rg) * 16 + kq] = make_float2(rsl[i], rsp[i]);
    float* redt = (float*)ldsApm;   // [64][16]
    #pragma unroll
    for (int i = 0; i < 4; i++) redt[(i * 16 + rg) * 16 + kq] = ts4[i];
    __syncthreads();

    if (t < NP) {
        float a = 0.f, c = 0.f;
        #pragma unroll
        for (int j = 0; j < 16; j++) { float2 v = red[t * 16 + j]; a += v.x; c += v.y; }
        const long rb = ((long)(b * nch + chunk) * NP + t) * 2;
        rspart[rb + 0] = a;
        rspart[rb + 1] = c;
    }
    if (t < MP) {
        float a = 0.f;
        #pragma unroll
        for (int j = 0; j < 16; j++) a += redt[t * 16 + j];
        tspart[(long)(b * nch + chunk) * MP + t] = a;
    }
}

// Epilogue: sum chunk partials, combine cls/mask/dice/style costs.
__global__ void matcher_epilogue(const float* __restrict__ pred_logits, // [4][100][2]
                                 const float* __restrict__ pred_style,  // [4][100][4]
                                 const int*   __restrict__ styles,      // [4][50]
                                 const float* __restrict__ part1,
                                 const float* __restrict__ part2,
                                 const float* __restrict__ rspart,
                                 const float* __restrict__ tspart,
                                 float* __restrict__ out, int nch)
{
    const int idx = blockIdx.x * 256 + threadIdx.x;
    if (idx >= BQ * NQ * MQ) return;
    const int m = idx % MQ;
    const int n = (idx / MQ) % NQ;
    const int b = idx / (NQ * MQ);

    float S1 = 0.f, S2 = 0.f, Sl = 0.f, Sp = 0.f, St = 0.f;
    for (int c = 0; c < nch; ++c) {
        const long base = (long)(b * nch + c);
        S1 += part1[base * NP * MP + n * MP + m];
        S2 += part2[base * NP * MP + n * MP + m];
        Sl += rspart[(base * NP + n) * 2 + 0];
        Sp += rspart[(base * NP + n) * 2 + 1];
        St += tspart[base * MP + m];
    }

    // classification: -softmax(logits)[1]
    const float l0 = pred_logits[(b * NQ + n) * 2 + 0];
    const float l1 = pred_logits[(b * NQ + n) * 2 + 1];
    const float p1 = 1.0f / (1.0f + __expf(l0 - l1));

    // style: -softmax(style)[sid]
    const float* st = &pred_style[(b * NQ + n) * 4];
    const float s0 = st[0], s1 = st[1], s2 = st[2], s3 = st[3];
    const float mx = fmaxf(fmaxf(s0, s1), fmaxf(s2, s3));
    const float e0 = __expf(s0 - mx), e1 = __expf(s1 - mx), e2 = __expf(s2 - mx), e3 = __expf(s3 - mx);
    const float esum = e0 + e1 + e2 + e3;
    int sid = styles[b * MQ + m];
    sid = min(max(sid, 0), 3);
    const float ps = (sid == 0 ? e0 : sid == 1 ? e1 : sid == 2 ? e2 : e3) / esum;

    const float cost_mask = -(S1 + Sl) * (1.0f / (float)HWSZ);
    const float dice = 1.0f - (2.0f * S2 + 1.0f) / (Sp + St + 1.0f);

    float c = 2.0f * (-p1) + 5.0f * cost_mask + 5.0f * dice + 1.0f * (-ps);
    if (isnan(c)) c = 10000.0f;
    else if (isinf(c)) c = (c > 0.f) ? 10000.0f : -10000.0f;
    out[idx] = c;
}

extern "C" void kernel_launch(void* const* d_in, const int* in_sizes, int n_in,
                              void* d_out, int out_size, void* d_ws, size_t ws_size,
                              hipStream_t stream) {
    const float* pred_logits = (const float*)d_in[0];
    const float* pred_masks  = (const float*)d_in[1];
    const float* pred_style  = (const float*)d_in[2];
    const float* tgt_masks   = (const float*)d_in[3];
    const int*   styles      = (const int*)d_in[4];
    float* out = (float*)d_out;

    // pick split-K chunk count that fits ws: bytes = nch * (2*4*112*64*4 + 4*112*2*4 + 4*64*4)
    int nch = 8;
    for (int cand = 128; cand >= 8; cand >>= 1) {
        size_t need = (size_t)cand * (2ull * BQ * NP * MP * 4ull + (size_t)BQ * NP * 2 * 4ull + (size_t)BQ * MP * 4ull);
        if (need <= ws_size) { nch = cand; break; }
    }
    const int Kc = HWSZ / nch;

    float* part1  = (float*)d_ws;
    float* part2  = part1 + (size_t)BQ * nch * NP * MP;
    float* rspart = part2 + (size_t)BQ * nch * NP * MP;
    float* tspart = rspart + (size_t)BQ * nch * NP * 2;

    dim3 grid(nch, BQ);
    matcher_main<<<grid, 256, 0, stream>>>(pred_masks, tgt_masks, part1, part2, rspart, tspart, nch, Kc);

    const int tot = BQ * NQ * MQ;
    matcher_epilogue<<<(tot + 255) / 256, 256, 0, stream>>>(
        pred_logits, pred_style, styles, part1, part2, rspart, tspart, out, nch);
}